// Round 6
// baseline (240.609 us; speedup 1.0000x reference)
//
#include <hip/hip_runtime.h>
#include <math.h>

#define WPB 4  // waves per block (block = 256 threads)

// Fused per-bit rotation (derivation in earlier rounds):
//   qubit n acts on global bit b = 9-n, theta_b = 0.5*sum_{l,k} ang[l][n][k].
//   Layers fuse (2D rotations on one bit compose by angle addition) and
//   cnot_matrix is the identity permutation.
//
// Layout (held end-to-end, loads AND stores coalesced float4):
//   element i = 256*m + 4*lane + k  ->  v[4*m+k]
//   reg bits {0,1}=k, {8,9}=m  -> in-register butterflies
//   lane bits: global bits 2..7 = lane bits 0..5:
//     xor1  -> DPP quad_perm [1,0,3,2]   (VALU)
//     xor2  -> DPP quad_perm [2,3,0,1]   (VALU)
//     xor4  -> ds_swizzle XOR            (DS)
//     xor8  -> DPP row_ror:8             (VALU)
//     xor16 -> permlane16_swap           (VALU)
//     xor32 -> permlane32_swap           (VALU)
//
// R4/R5 changes (spill fix — R3 post-mortem):
//   * __launch_bounds__(256, 4): VGPR budget 128 (was heuristic-capped at 40,
//     forcing the ~70-reg live set to spill to scratch every row — the 83 us
//     wall both prior rounds shared).
//   * cb/sb hoisted to SGPRs via readfirstlane (wave-uniform; -20 VGPRs).
//   * non-temporal stores via clang ext_vector f32x4 (float4 is a
//     HIP_vector_type class — the builtin rejects it; R4 compile fail).

typedef float f32x4 __attribute__((ext_vector_type(4)));

#define DPP_XOR1 0xB1   // quad_perm [1,0,3,2]
#define DPP_XOR2 0x4E   // quad_perm [2,3,0,1]
#define DPP_XOR8 0x128  // row_ror:8

template <int CTRL>
__device__ __forceinline__ float fdpp(float v) {
    return __int_as_float(
        __builtin_amdgcn_mov_dpp(__float_as_int(v), CTRL, 0xF, 0xF, false));
}

__device__ __forceinline__ float rfl(float v) {
    return __int_as_float(__builtin_amdgcn_readfirstlane(__float_as_int(v)));
}

__global__ __launch_bounds__(256, 4) void qel_r5(
    const float* __restrict__ x,
    const float* __restrict__ ang,   // [4][10][3]
    float* __restrict__ out,
    int rows)
{
    const int tid  = threadIdx.x;
    const int lane = tid & 63;

    float cb[10], sb[10];
#pragma unroll
    for (int n = 0; n < 10; ++n) {
        float t = 0.f;
#pragma unroll
        for (int l = 0; l < 4; ++l) {
            const float* a = ang + (l * 10 + n) * 3;
            t += a[0] + a[1] + a[2];
        }
        t *= 0.5f;
        sincosf(t, &sb[9 - n], &cb[9 - n]);
    }
    // Wave-uniform -> park in SGPRs (VALU reads 1 SGPR operand for free).
#pragma unroll
    for (int b = 0; b < 10; ++b) { cb[b] = rfl(cb[b]); sb[b] = rfl(sb[b]); }

    // Signed sine for lane-bit stages B=0..5:
    //   bit==0: v' = c*v - s*p ; bit==1: v' = s*p + c*v  ->  v' = fma(c,v,se*p)
    float se[6];
#pragma unroll
    for (int B = 0; B < 6; ++B)
        se[B] = ((lane >> B) & 1) ? sb[B + 2] : -sb[B + 2];

    // (alpha,beta) form for permlane-swap stages: builtin returns
    //   r0 = (bit ? partner : self), r1 = (bit ? self : partner)
    //   v' = alpha*r0 + beta*r1 ; bit==0: (c,-s) ; bit==1: (s,c)
    const float a16 = (lane & 16) ? sb[6] : cb[6];
    const float b16 = (lane & 16) ? cb[6] : -sb[6];
    const float a32 = (lane & 32) ? sb[7] : cb[7];
    const float b32 = (lane & 32) ? cb[7] : -sb[7];

    const int waveId = blockIdx.x * WPB + (tid >> 6);
    const int nW     = gridDim.x * WPB;

#define LOADROW(V, R)                                                       \
    do {                                                                    \
        const float* xr_ = x + (size_t)(R) * 1024;                          \
        _Pragma("unroll")                                                   \
        for (int m = 0; m < 4; ++m) {                                       \
            const f32x4 t4 = *(const f32x4*)(xr_ + 256 * m + 4 * lane);     \
            V[4*m+0]=t4.x; V[4*m+1]=t4.y; V[4*m+2]=t4.z; V[4*m+3]=t4.w;     \
        }                                                                   \
    } while (0)

#define RSTAGE(V, P, CC, SS)                                                \
    do {                                                                    \
        _Pragma("unroll")                                                   \
        for (int q = 0; q < 16; ++q)                                        \
            if ((q & (1 << (P))) == 0) {                                    \
                const float lo = V[q], hi = V[q | (1 << (P))];              \
                V[q]              = (CC) * lo - (SS) * hi;                  \
                V[q | (1 << (P))] = (SS) * lo + (CC) * hi;                  \
            }                                                               \
    } while (0)

#define DPPSTAGE(V, CTRL, CC, SE)                                           \
    do {                                                                    \
        float p_[16];                                                       \
        _Pragma("unroll")                                                   \
        for (int q = 0; q < 16; ++q) p_[q] = fdpp<CTRL>(V[q]);              \
        _Pragma("unroll")                                                   \
        for (int q = 0; q < 16; ++q)                                        \
            V[q] = fmaf((CC), V[q], (SE) * p_[q]);                          \
    } while (0)

#define DSSTAGE(V, IMM, CC, SE)                                             \
    do {                                                                    \
        float p_[16];                                                       \
        _Pragma("unroll")                                                   \
        for (int q = 0; q < 16; ++q)                                        \
            p_[q] = __int_as_float(__builtin_amdgcn_ds_swizzle(             \
                        __float_as_int(V[q]), (IMM)));                      \
        _Pragma("unroll")                                                   \
        for (int q = 0; q < 16; ++q)                                        \
            V[q] = fmaf((CC), V[q], (SE) * p_[q]);                          \
    } while (0)

#if defined(__has_builtin) && __has_builtin(__builtin_amdgcn_permlane16_swap)
#define PL16STAGE(V)                                                        \
    do {                                                                    \
        _Pragma("unroll")                                                   \
        for (int q = 0; q < 16; ++q) {                                      \
            const int s_ = __float_as_int(V[q]);                            \
            auto r_ = __builtin_amdgcn_permlane16_swap(s_, s_, false, false);\
            V[q] = fmaf(a16, __int_as_float(r_[0]),                         \
                        b16 * __int_as_float(r_[1]));                       \
        }                                                                   \
    } while (0)
#else
#define PL16STAGE(V) DSSTAGE(V, 0x401F, cb[6], se[4])
#endif

#if defined(__has_builtin) && __has_builtin(__builtin_amdgcn_permlane32_swap)
#define PL32STAGE(V)                                                        \
    do {                                                                    \
        _Pragma("unroll")                                                   \
        for (int q = 0; q < 16; ++q) {                                      \
            const int s_ = __float_as_int(V[q]);                            \
            auto r_ = __builtin_amdgcn_permlane32_swap(s_, s_, false, false);\
            V[q] = fmaf(a32, __int_as_float(r_[0]),                         \
                        b32 * __int_as_float(r_[1]));                       \
        }                                                                   \
    } while (0)
#else
#define PL32STAGE(V)                                                        \
    do {                                                                    \
        float p_[16];                                                       \
        _Pragma("unroll")                                                   \
        for (int q = 0; q < 16; ++q) p_[q] = __shfl_xor(V[q], 32, 64);      \
        _Pragma("unroll")                                                   \
        for (int q = 0; q < 16; ++q)                                        \
            V[q] = fmaf(cb[7], V[q], se[5] * p_[q]);                        \
    } while (0)
#endif

#define PROCESS_STORE(V, R)                                                 \
    do {                                                                    \
        RSTAGE(V, 0, cb[0], sb[0]);   /* global bit 0 */                    \
        RSTAGE(V, 1, cb[1], sb[1]);   /* global bit 1 */                    \
        RSTAGE(V, 2, cb[8], sb[8]);   /* global bit 8 */                    \
        RSTAGE(V, 3, cb[9], sb[9]);   /* global bit 9 */                    \
        DPPSTAGE(V, DPP_XOR1, cb[2], se[0]);   /* bit 2 */                  \
        DPPSTAGE(V, DPP_XOR2, cb[3], se[1]);   /* bit 3 */                  \
        DSSTAGE (V, 0x101F,   cb[4], se[2]);   /* bit 4 (xor4, DS pipe) */  \
        DPPSTAGE(V, DPP_XOR8, cb[5], se[3]);   /* bit 5 */                  \
        PL16STAGE(V);                          /* bit 6 (xor16) */          \
        PL32STAGE(V);                          /* bit 7 (xor32) */          \
        float* yr_ = out + (size_t)(R) * 1024;                              \
        _Pragma("unroll")                                                   \
        for (int m = 0; m < 4; ++m) {                                       \
            f32x4 t4;                                                       \
            t4.x = V[4*m+0]; t4.y = V[4*m+1];                               \
            t4.z = V[4*m+2]; t4.w = V[4*m+3];                               \
            __builtin_nontemporal_store(t4,                                 \
                (f32x4*)(yr_ + 256 * m + 4 * lane));                        \
        }                                                                   \
    } while (0)

    // Ping-pong prefetch (now that the buffers actually live in registers):
    // next row's loads issue before the current row's ~900-cycle chain.
    int r0 = waveId;
    if (r0 >= rows) return;
    float A[16], B[16];
    LOADROW(A, r0);
    while (true) {
        int r1 = r0 + nW;
        if (r1 < rows) LOADROW(B, r1);
        PROCESS_STORE(A, r0);
        if (r1 >= rows) break;
        r0 = r1 + nW;
        if (r0 < rows) LOADROW(A, r0);
        PROCESS_STORE(B, r1);
        if (r0 >= rows) break;
    }

#undef LOADROW
#undef RSTAGE
#undef DPPSTAGE
#undef DSSTAGE
#undef PL16STAGE
#undef PL32STAGE
#undef PROCESS_STORE
}

extern "C" void kernel_launch(void* const* d_in, const int* in_sizes, int n_in,
                              void* d_out, int out_size, void* d_ws, size_t ws_size,
                              hipStream_t stream) {
    const float* x   = (const float*)d_in[0];
    const float* ang = (const float*)d_in[1];
    // d_in[2] (cnot_matrix) is provably the identity permutation -> unused.
    float* out = (float*)d_out;
    const int rows = in_sizes[0] / 1024;   // 32768
    int blocks = (rows + WPB - 1) / WPB;
    if (blocks > 2048) blocks = 2048;      // grid-stride, 4 rows/wave
    qel_r5<<<blocks, 256, 0, stream>>>(x, ang, out, rows);
}

// Round 7
// 240.336 us; speedup vs baseline: 1.0011x; 1.0011x over previous
//
#include <hip/hip_runtime.h>
#include <math.h>

#define WPB 4  // waves per block (block = 256 threads)

// Fused per-bit rotation (derivation in earlier rounds):
//   qubit n acts on global bit b = 9-n, theta_b = 0.5*sum_{l,k} ang[l][n][k].
//   Layers fuse (2D rotations on one bit compose by angle addition) and
//   cnot_matrix is the identity permutation.
//
// Layout (held end-to-end, loads AND stores coalesced float4):
//   element i = 256*m + 4*lane + k  ->  v[4*m+k]
//   reg bits {0,1}=k, {8,9}=m  -> in-register butterflies
//   lane bits: global bits 2..7 = lane bits 0..5:
//     xor1  -> DPP quad_perm [1,0,3,2]   (VALU)
//     xor2  -> DPP quad_perm [2,3,0,1]   (VALU)
//     xor4  -> ds_swizzle XOR            (DS)
//     xor8  -> DPP row_ror:8             (VALU)
//     xor16 -> permlane16_swap           (VALU)
//     xor32 -> permlane32_swap           (VALU)
//
// R7 (MLP fix — R6 post-mortem): R2/R3/R6 all hit the same 83-86 us wall at
// 2.4 TB/s with nothing saturated; each wave ran rows serially (one 4 KB load
// batch in flight ~25% of the time) and the compiler sank every prefetch
// (VGPR=36 proves A/B never coexisted). Fix:
//   * 2 rows per wave, BOTH loaded upfront (8 KB in flight), stages
//     INTERLEAVED A-then-B so B's loads are consumed 2nd in program order —
//     sinking them is never profitable. Also 2x VALU ILP.
//   * no per-wave loop: 4096 blocks x 4 waves = 16384 waves, high churn.
//   * plain stores (nt was neutral-to-worse in R6).

typedef float f32x4 __attribute__((ext_vector_type(4)));

#define DPP_XOR1 0xB1   // quad_perm [1,0,3,2]
#define DPP_XOR2 0x4E   // quad_perm [2,3,0,1]
#define DPP_XOR8 0x128  // row_ror:8

template <int CTRL>
__device__ __forceinline__ float fdpp(float v) {
    return __int_as_float(
        __builtin_amdgcn_mov_dpp(__float_as_int(v), CTRL, 0xF, 0xF, false));
}

__device__ __forceinline__ float rfl(float v) {
    return __int_as_float(__builtin_amdgcn_readfirstlane(__float_as_int(v)));
}

__global__ __launch_bounds__(256, 4) void qel_r7(
    const float* __restrict__ x,
    const float* __restrict__ ang,   // [4][10][3]
    float* __restrict__ out,
    int rows)
{
    const int tid  = threadIdx.x;
    const int lane = tid & 63;

    float cb[10], sb[10];
#pragma unroll
    for (int n = 0; n < 10; ++n) {
        float t = 0.f;
#pragma unroll
        for (int l = 0; l < 4; ++l) {
            const float* a = ang + (l * 10 + n) * 3;
            t += a[0] + a[1] + a[2];
        }
        t *= 0.5f;
        sincosf(t, &sb[9 - n], &cb[9 - n]);
    }
    // Wave-uniform -> park in SGPRs.
#pragma unroll
    for (int b = 0; b < 10; ++b) { cb[b] = rfl(cb[b]); sb[b] = rfl(sb[b]); }

    // Signed sine for lane-bit stages B=0..5:
    //   bit==0: v' = c*v - s*p ; bit==1: v' = s*p + c*v  ->  v' = fma(c,v,se*p)
    float se[6];
#pragma unroll
    for (int B = 0; B < 6; ++B)
        se[B] = ((lane >> B) & 1) ? sb[B + 2] : -sb[B + 2];

    // (alpha,beta) form for permlane-swap stages: builtin returns
    //   r0 = (bit ? partner : self), r1 = (bit ? self : partner)
    //   v' = alpha*r0 + beta*r1 ; bit==0: (c,-s) ; bit==1: (s,c)
    const float a16 = (lane & 16) ? sb[6] : cb[6];
    const float b16 = (lane & 16) ? cb[6] : -sb[6];
    const float a32 = (lane & 32) ? sb[7] : cb[7];
    const float b32 = (lane & 32) ? cb[7] : -sb[7];

    const int waveId = blockIdx.x * WPB + (tid >> 6);

#define LOADROW(V, R)                                                       \
    do {                                                                    \
        const float* xr_ = x + (size_t)(R) * 1024;                          \
        _Pragma("unroll")                                                   \
        for (int m = 0; m < 4; ++m) {                                       \
            const f32x4 t4 = *(const f32x4*)(xr_ + 256 * m + 4 * lane);     \
            V[4*m+0]=t4.x; V[4*m+1]=t4.y; V[4*m+2]=t4.z; V[4*m+3]=t4.w;     \
        }                                                                   \
    } while (0)

#define RSTAGE(V, P, CC, SS)                                                \
    do {                                                                    \
        _Pragma("unroll")                                                   \
        for (int q = 0; q < 16; ++q)                                        \
            if ((q & (1 << (P))) == 0) {                                    \
                const float lo = V[q], hi = V[q | (1 << (P))];              \
                V[q]              = (CC) * lo - (SS) * hi;                  \
                V[q | (1 << (P))] = (SS) * lo + (CC) * hi;                  \
            }                                                               \
    } while (0)

#define DPPSTAGE(V, CTRL, CC, SE)                                           \
    do {                                                                    \
        float p_[16];                                                       \
        _Pragma("unroll")                                                   \
        for (int q = 0; q < 16; ++q) p_[q] = fdpp<CTRL>(V[q]);              \
        _Pragma("unroll")                                                   \
        for (int q = 0; q < 16; ++q)                                        \
            V[q] = fmaf((CC), V[q], (SE) * p_[q]);                          \
    } while (0)

#define DSSTAGE(V, IMM, CC, SE)                                             \
    do {                                                                    \
        float p_[16];                                                       \
        _Pragma("unroll")                                                   \
        for (int q = 0; q < 16; ++q)                                        \
            p_[q] = __int_as_float(__builtin_amdgcn_ds_swizzle(             \
                        __float_as_int(V[q]), (IMM)));                      \
        _Pragma("unroll")                                                   \
        for (int q = 0; q < 16; ++q)                                        \
            V[q] = fmaf((CC), V[q], (SE) * p_[q]);                          \
    } while (0)

#if defined(__has_builtin) && __has_builtin(__builtin_amdgcn_permlane16_swap)
#define PL16STAGE(V)                                                        \
    do {                                                                    \
        _Pragma("unroll")                                                   \
        for (int q = 0; q < 16; ++q) {                                      \
            const int s_ = __float_as_int(V[q]);                            \
            auto r_ = __builtin_amdgcn_permlane16_swap(s_, s_, false, false);\
            V[q] = fmaf(a16, __int_as_float(r_[0]),                         \
                        b16 * __int_as_float(r_[1]));                       \
        }                                                                   \
    } while (0)
#else
#define PL16STAGE(V) DSSTAGE(V, 0x401F, cb[6], se[4])
#endif

#if defined(__has_builtin) && __has_builtin(__builtin_amdgcn_permlane32_swap)
#define PL32STAGE(V)                                                        \
    do {                                                                    \
        _Pragma("unroll")                                                   \
        for (int q = 0; q < 16; ++q) {                                      \
            const int s_ = __float_as_int(V[q]);                            \
            auto r_ = __builtin_amdgcn_permlane32_swap(s_, s_, false, false);\
            V[q] = fmaf(a32, __int_as_float(r_[0]),                         \
                        b32 * __int_as_float(r_[1]));                       \
        }                                                                   \
    } while (0)
#else
#define PL32STAGE(V)                                                        \
    do {                                                                    \
        float p_[16];                                                       \
        _Pragma("unroll")                                                   \
        for (int q = 0; q < 16; ++q) p_[q] = __shfl_xor(V[q], 32, 64);      \
        _Pragma("unroll")                                                   \
        for (int q = 0; q < 16; ++q)                                        \
            V[q] = fmaf(cb[7], V[q], se[5] * p_[q]);                        \
    } while (0)
#endif

#define STOREROW(V, R)                                                      \
    do {                                                                    \
        float* yr_ = out + (size_t)(R) * 1024;                              \
        _Pragma("unroll")                                                   \
        for (int m = 0; m < 4; ++m) {                                       \
            f32x4 t4;                                                       \
            t4.x = V[4*m+0]; t4.y = V[4*m+1];                               \
            t4.z = V[4*m+2]; t4.w = V[4*m+3];                               \
            *(f32x4*)(yr_ + 256 * m + 4 * lane) = t4;                       \
        }                                                                   \
    } while (0)

// all 10 stages for one row-buffer (order identical to prior rounds)
#define ALLSTAGES(V)                                                        \
    do {                                                                    \
        RSTAGE(V, 0, cb[0], sb[0]);            /* global bit 0 */           \
        RSTAGE(V, 1, cb[1], sb[1]);            /* global bit 1 */           \
        RSTAGE(V, 2, cb[8], sb[8]);            /* global bit 8 */           \
        RSTAGE(V, 3, cb[9], sb[9]);            /* global bit 9 */           \
        DPPSTAGE(V, DPP_XOR1, cb[2], se[0]);   /* bit 2 */                  \
        DPPSTAGE(V, DPP_XOR2, cb[3], se[1]);   /* bit 3 */                  \
        DSSTAGE (V, 0x101F,   cb[4], se[2]);   /* bit 4 (xor4, DS pipe) */  \
        DPPSTAGE(V, DPP_XOR8, cb[5], se[3]);   /* bit 5 */                  \
        PL16STAGE(V);                          /* bit 6 (xor16) */          \
        PL32STAGE(V);                          /* bit 7 (xor32) */          \
    } while (0)

    const int r0 = waveId * 2;
    const int r1 = r0 + 1;
    if (r0 >= rows) return;

    float A[16], B[16];
    if (r1 < rows) {
        // Pair path: both rows' loads issue upfront (8 KB in flight),
        // stages interleaved A-then-B -> B's loads consumed 2nd in program
        // order, so the scheduler cannot profitably sink them.
        LOADROW(A, r0);
        LOADROW(B, r1);
        RSTAGE(A, 0, cb[0], sb[0]);            RSTAGE(B, 0, cb[0], sb[0]);
        RSTAGE(A, 1, cb[1], sb[1]);            RSTAGE(B, 1, cb[1], sb[1]);
        RSTAGE(A, 2, cb[8], sb[8]);            RSTAGE(B, 2, cb[8], sb[8]);
        RSTAGE(A, 3, cb[9], sb[9]);            RSTAGE(B, 3, cb[9], sb[9]);
        DPPSTAGE(A, DPP_XOR1, cb[2], se[0]);   DPPSTAGE(B, DPP_XOR1, cb[2], se[0]);
        DPPSTAGE(A, DPP_XOR2, cb[3], se[1]);   DPPSTAGE(B, DPP_XOR2, cb[3], se[1]);
        DSSTAGE (A, 0x101F,   cb[4], se[2]);   DSSTAGE (B, 0x101F,   cb[4], se[2]);
        DPPSTAGE(A, DPP_XOR8, cb[5], se[3]);   DPPSTAGE(B, DPP_XOR8, cb[5], se[3]);
        PL16STAGE(A);                          PL16STAGE(B);
        PL32STAGE(A);                          PL32STAGE(B);
        STOREROW(A, r0);
        STOREROW(B, r1);
    } else {
        LOADROW(A, r0);
        ALLSTAGES(A);
        STOREROW(A, r0);
    }

#undef LOADROW
#undef RSTAGE
#undef DPPSTAGE
#undef DSSTAGE
#undef PL16STAGE
#undef PL32STAGE
#undef STOREROW
#undef ALLSTAGES
}

extern "C" void kernel_launch(void* const* d_in, const int* in_sizes, int n_in,
                              void* d_out, int out_size, void* d_ws, size_t ws_size,
                              hipStream_t stream) {
    const float* x   = (const float*)d_in[0];
    const float* ang = (const float*)d_in[1];
    // d_in[2] (cnot_matrix) is provably the identity permutation -> unused.
    float* out = (float*)d_out;
    const int rows = in_sizes[0] / 1024;           // 32768
    const int pairs = (rows + 1) / 2;              // rows per wave-pair
    int blocks = (pairs + WPB - 1) / WPB;          // 4096 for rows=32768
    qel_r7<<<blocks, 256, 0, stream>>>(x, ang, out, rows);
}

// Round 8
// 239.937 us; speedup vs baseline: 1.0028x; 1.0017x over previous
//
#include <hip/hip_runtime.h>
#include <math.h>

#define WPB 4  // waves per block (block = 256 threads)

// Fused per-bit rotation (derivation in earlier rounds):
//   qubit n acts on global bit b = 9-n, theta_b = 0.5*sum_{l,k} ang[l][n][k].
//   Layers fuse (2D rotations on one bit compose by angle addition) and
//   cnot_matrix is the identity permutation.
//
// Layout (held end-to-end, loads AND stores coalesced float4):
//   element i = 256*m + 4*lane + k  ->  v[4*m+k]
//   reg bits {0,1}=k, {8,9}=m  -> in-register butterflies
//   lane bits: global bits 2..7 = lane bits 0..5:
//     xor1  -> DPP quad_perm [1,0,3,2]   (VALU)
//     xor2  -> DPP quad_perm [2,3,0,1]   (VALU)
//     xor4  -> ds_swizzle XOR            (DS)
//     xor8  -> DPP row_ror:8             (VALU)
//     xor16 -> permlane16_swap           (VALU)
//     xor32 -> permlane32_swap           (VALU)
//
// R8 (register-pin MLP test — R7 post-mortem): R7's source-level A/B
// interleave was legally de-interleaved by the list scheduler (VGPR=32
// proves A and B never coexisted; independent chains got serialized to
// minimize pressure). Program order does not bind an SSA scheduler — a
// hard use-point does. Fix: asm volatile("" :: "v"(reg)) pins after both
// LOADROWs force all 32 values materialized -> 8 KB in flight per wave,
// loads issued upfront, allocator must carry both buffers. If this still
// lands at ~85 us with VGPR~70, the ~2.35 TB/s is a pattern ceiling (H2)
// and we are at the roofline.

typedef float f32x4 __attribute__((ext_vector_type(4)));

#define DPP_XOR1 0xB1   // quad_perm [1,0,3,2]
#define DPP_XOR2 0x4E   // quad_perm [2,3,0,1]
#define DPP_XOR8 0x128  // row_ror:8

template <int CTRL>
__device__ __forceinline__ float fdpp(float v) {
    return __int_as_float(
        __builtin_amdgcn_mov_dpp(__float_as_int(v), CTRL, 0xF, 0xF, false));
}

__device__ __forceinline__ float rfl(float v) {
    return __int_as_float(__builtin_amdgcn_readfirstlane(__float_as_int(v)));
}

__global__ __launch_bounds__(256, 4) void qel_r8(
    const float* __restrict__ x,
    const float* __restrict__ ang,   // [4][10][3]
    float* __restrict__ out,
    int rows)
{
    const int tid  = threadIdx.x;
    const int lane = tid & 63;

    float cb[10], sb[10];
#pragma unroll
    for (int n = 0; n < 10; ++n) {
        float t = 0.f;
#pragma unroll
        for (int l = 0; l < 4; ++l) {
            const float* a = ang + (l * 10 + n) * 3;
            t += a[0] + a[1] + a[2];
        }
        t *= 0.5f;
        sincosf(t, &sb[9 - n], &cb[9 - n]);
    }
    // Wave-uniform -> park in SGPRs.
#pragma unroll
    for (int b = 0; b < 10; ++b) { cb[b] = rfl(cb[b]); sb[b] = rfl(sb[b]); }

    // Signed sine for lane-bit stages B=0..5:
    //   bit==0: v' = c*v - s*p ; bit==1: v' = s*p + c*v  ->  v' = fma(c,v,se*p)
    float se[6];
#pragma unroll
    for (int B = 0; B < 6; ++B)
        se[B] = ((lane >> B) & 1) ? sb[B + 2] : -sb[B + 2];

    // (alpha,beta) form for permlane-swap stages: builtin returns
    //   r0 = (bit ? partner : self), r1 = (bit ? self : partner)
    //   v' = alpha*r0 + beta*r1 ; bit==0: (c,-s) ; bit==1: (s,c)
    const float a16 = (lane & 16) ? sb[6] : cb[6];
    const float b16 = (lane & 16) ? cb[6] : -sb[6];
    const float a32 = (lane & 32) ? sb[7] : cb[7];
    const float b32 = (lane & 32) ? cb[7] : -sb[7];

    const int waveId = blockIdx.x * WPB + (tid >> 6);

#define LOADROW(V, R)                                                       \
    do {                                                                    \
        const float* xr_ = x + (size_t)(R) * 1024;                          \
        _Pragma("unroll")                                                   \
        for (int m = 0; m < 4; ++m) {                                       \
            const f32x4 t4 = *(const f32x4*)(xr_ + 256 * m + 4 * lane);     \
            V[4*m+0]=t4.x; V[4*m+1]=t4.y; V[4*m+2]=t4.z; V[4*m+3]=t4.w;     \
        }                                                                   \
    } while (0)

// Unmovable use-point: forces all 16 values of V to be materialized in
// VGPRs here (loads issued & completed before this point; allocator must
// keep them live). Empty asm emits no instructions.
#define PIN16(V)                                                            \
    asm volatile("" ::                                                      \
        "v"(V[0]),  "v"(V[1]),  "v"(V[2]),  "v"(V[3]),                      \
        "v"(V[4]),  "v"(V[5]),  "v"(V[6]),  "v"(V[7]),                      \
        "v"(V[8]),  "v"(V[9]),  "v"(V[10]), "v"(V[11]),                     \
        "v"(V[12]), "v"(V[13]), "v"(V[14]), "v"(V[15]))

#define RSTAGE(V, P, CC, SS)                                                \
    do {                                                                    \
        _Pragma("unroll")                                                   \
        for (int q = 0; q < 16; ++q)                                        \
            if ((q & (1 << (P))) == 0) {                                    \
                const float lo = V[q], hi = V[q | (1 << (P))];              \
                V[q]              = (CC) * lo - (SS) * hi;                  \
                V[q | (1 << (P))] = (SS) * lo + (CC) * hi;                  \
            }                                                               \
    } while (0)

#define DPPSTAGE(V, CTRL, CC, SE)                                           \
    do {                                                                    \
        float p_[16];                                                       \
        _Pragma("unroll")                                                   \
        for (int q = 0; q < 16; ++q) p_[q] = fdpp<CTRL>(V[q]);              \
        _Pragma("unroll")                                                   \
        for (int q = 0; q < 16; ++q)                                        \
            V[q] = fmaf((CC), V[q], (SE) * p_[q]);                          \
    } while (0)

#define DSSTAGE(V, IMM, CC, SE)                                             \
    do {                                                                    \
        float p_[16];                                                       \
        _Pragma("unroll")                                                   \
        for (int q = 0; q < 16; ++q)                                        \
            p_[q] = __int_as_float(__builtin_amdgcn_ds_swizzle(             \
                        __float_as_int(V[q]), (IMM)));                      \
        _Pragma("unroll")                                                   \
        for (int q = 0; q < 16; ++q)                                        \
            V[q] = fmaf((CC), V[q], (SE) * p_[q]);                          \
    } while (0)

#if defined(__has_builtin) && __has_builtin(__builtin_amdgcn_permlane16_swap)
#define PL16STAGE(V)                                                        \
    do {                                                                    \
        _Pragma("unroll")                                                   \
        for (int q = 0; q < 16; ++q) {                                      \
            const int s_ = __float_as_int(V[q]);                            \
            auto r_ = __builtin_amdgcn_permlane16_swap(s_, s_, false, false);\
            V[q] = fmaf(a16, __int_as_float(r_[0]),                         \
                        b16 * __int_as_float(r_[1]));                       \
        }                                                                   \
    } while (0)
#else
#define PL16STAGE(V) DSSTAGE(V, 0x401F, cb[6], se[4])
#endif

#if defined(__has_builtin) && __has_builtin(__builtin_amdgcn_permlane32_swap)
#define PL32STAGE(V)                                                        \
    do {                                                                    \
        _Pragma("unroll")                                                   \
        for (int q = 0; q < 16; ++q) {                                      \
            const int s_ = __float_as_int(V[q]);                            \
            auto r_ = __builtin_amdgcn_permlane32_swap(s_, s_, false, false);\
            V[q] = fmaf(a32, __int_as_float(r_[0]),                         \
                        b32 * __int_as_float(r_[1]));                       \
        }                                                                   \
    } while (0)
#else
#define PL32STAGE(V)                                                        \
    do {                                                                    \
        float p_[16];                                                       \
        _Pragma("unroll")                                                   \
        for (int q = 0; q < 16; ++q) p_[q] = __shfl_xor(V[q], 32, 64);      \
        _Pragma("unroll")                                                   \
        for (int q = 0; q < 16; ++q)                                        \
            V[q] = fmaf(cb[7], V[q], se[5] * p_[q]);                        \
    } while (0)
#endif

#define STOREROW(V, R)                                                      \
    do {                                                                    \
        float* yr_ = out + (size_t)(R) * 1024;                              \
        _Pragma("unroll")                                                   \
        for (int m = 0; m < 4; ++m) {                                       \
            f32x4 t4;                                                       \
            t4.x = V[4*m+0]; t4.y = V[4*m+1];                               \
            t4.z = V[4*m+2]; t4.w = V[4*m+3];                               \
            *(f32x4*)(yr_ + 256 * m + 4 * lane) = t4;                       \
        }                                                                   \
    } while (0)

// all 10 stages for one row-buffer (order identical to prior rounds)
#define ALLSTAGES(V)                                                        \
    do {                                                                    \
        RSTAGE(V, 0, cb[0], sb[0]);            /* global bit 0 */           \
        RSTAGE(V, 1, cb[1], sb[1]);            /* global bit 1 */           \
        RSTAGE(V, 2, cb[8], sb[8]);            /* global bit 8 */           \
        RSTAGE(V, 3, cb[9], sb[9]);            /* global bit 9 */           \
        DPPSTAGE(V, DPP_XOR1, cb[2], se[0]);   /* bit 2 */                  \
        DPPSTAGE(V, DPP_XOR2, cb[3], se[1]);   /* bit 3 */                  \
        DSSTAGE (V, 0x101F,   cb[4], se[2]);   /* bit 4 (xor4, DS pipe) */  \
        DPPSTAGE(V, DPP_XOR8, cb[5], se[3]);   /* bit 5 */                  \
        PL16STAGE(V);                          /* bit 6 (xor16) */          \
        PL32STAGE(V);                          /* bit 7 (xor32) */          \
    } while (0)

    const int r0 = waveId * 2;
    const int r1 = r0 + 1;
    if (r0 >= rows) return;

    float A[16], B[16];
    if (r1 < rows) {
        // Both rows' loads issue upfront (8 KB in flight per wave); the
        // PIN16s are unmovable use-points, so the scheduler can neither
        // sink B's loads nor de-interleave by spilling a buffer.
        LOADROW(A, r0);
        LOADROW(B, r1);
        PIN16(A);
        PIN16(B);
        RSTAGE(A, 0, cb[0], sb[0]);            RSTAGE(B, 0, cb[0], sb[0]);
        RSTAGE(A, 1, cb[1], sb[1]);            RSTAGE(B, 1, cb[1], sb[1]);
        RSTAGE(A, 2, cb[8], sb[8]);            RSTAGE(B, 2, cb[8], sb[8]);
        RSTAGE(A, 3, cb[9], sb[9]);            RSTAGE(B, 3, cb[9], sb[9]);
        DPPSTAGE(A, DPP_XOR1, cb[2], se[0]);   DPPSTAGE(B, DPP_XOR1, cb[2], se[0]);
        DPPSTAGE(A, DPP_XOR2, cb[3], se[1]);   DPPSTAGE(B, DPP_XOR2, cb[3], se[1]);
        DSSTAGE (A, 0x101F,   cb[4], se[2]);   DSSTAGE (B, 0x101F,   cb[4], se[2]);
        DPPSTAGE(A, DPP_XOR8, cb[5], se[3]);   DPPSTAGE(B, DPP_XOR8, cb[5], se[3]);
        PL16STAGE(A);                          PL16STAGE(B);
        PL32STAGE(A);                          PL32STAGE(B);
        STOREROW(A, r0);
        STOREROW(B, r1);
    } else {
        LOADROW(A, r0);
        ALLSTAGES(A);
        STOREROW(A, r0);
    }

#undef LOADROW
#undef PIN16
#undef RSTAGE
#undef DPPSTAGE
#undef DSSTAGE
#undef PL16STAGE
#undef PL32STAGE
#undef STOREROW
#undef ALLSTAGES
}

extern "C" void kernel_launch(void* const* d_in, const int* in_sizes, int n_in,
                              void* d_out, int out_size, void* d_ws, size_t ws_size,
                              hipStream_t stream) {
    const float* x   = (const float*)d_in[0];
    const float* ang = (const float*)d_in[1];
    // d_in[2] (cnot_matrix) is provably the identity permutation -> unused.
    float* out = (float*)d_out;
    const int rows = in_sizes[0] / 1024;           // 32768
    const int pairs = (rows + 1) / 2;              // one pair of rows per wave
    int blocks = (pairs + WPB - 1) / WPB;          // 4096 for rows=32768
    qel_r8<<<blocks, 256, 0, stream>>>(x, ang, out, rows);
}